// Round 3
// baseline (903.533 us; speedup 1.0000x reference)
//
#include <hip/hip_runtime.h>
#include <math.h>

// Problem constants (reference: B=32, L=2048)
#define LLEN 2048
#define BATCH 32
#define N_PTS (LLEN - 2)     // 2046 embedded points
#define N_DEATH (LLEN - 3)   // 2045 MST edges / deaths
#define SORT_N 2048
#define TPB 256              // 4 waves; wave 0 runs Prim solo, all sort
#define NW 4
#define BIG 1e30f
#define TOPO_BYTES ((size_t)64 * N_DEATH * 4)   // 523,520 B

typedef float v2f __attribute__((ext_vector_type(2)));

// Wave64 unsigned-min via DPP (VALU pipe). Result valid in lane 63.
__device__ __forceinline__ unsigned dpp_umin6(unsigned v) {
    unsigned t;
    t = (unsigned)__builtin_amdgcn_update_dpp(-1, (int)v, 0x111, 0xF, 0xF, false); // row_shr:1
    v = t < v ? t : v;
    t = (unsigned)__builtin_amdgcn_update_dpp(-1, (int)v, 0x112, 0xF, 0xF, false); // row_shr:2
    v = t < v ? t : v;
    t = (unsigned)__builtin_amdgcn_update_dpp(-1, (int)v, 0x114, 0xF, 0xF, false); // row_shr:4
    v = t < v ? t : v;
    t = (unsigned)__builtin_amdgcn_update_dpp(-1, (int)v, 0x118, 0xF, 0xF, false); // row_shr:8
    v = t < v ? t : v;
    t = (unsigned)__builtin_amdgcn_update_dpp(-1, (int)v, 0x142, 0xF, 0xF, false); // row_bcast:15
    v = t < v ? t : v;
    t = (unsigned)__builtin_amdgcn_update_dpp(-1, (int)v, 0x143, 0xF, 0xF, false); // row_bcast:31
    v = t < v ? t : v;
    return v;
}

// ROUND-8: solo-wave Prim with progressive wave-local compaction.
// Wave 0 owns the whole series: argmin = DPP reduce + readlane broadcast
// (no mailbox / no barrier / no xslot read — deletes ~210 cyc/iter of
// exchange). When remaining candidates <= 64*Knext, compact survivors
// (positions+keys from registers) into pp[0..rem) (pos.xyz + key in .w),
// halving the scan repeatedly: K = 32,24,16,12,8,6,4,2.
// Correctness: keys are truncated d2 (as in prior passing rounds); any
// argmin tie-break yields the same sorted MST edge-weight multiset, and
// deaths are exactly those truncated weights -> sorted output unchanged.
// Waves 1-3 park at the first sort __syncthreads (wave 0's solo region
// has ZERO barriers, so the rendezvous counts stay aligned).
template<int K, bool FIRST, bool COMPACT>
__device__ __forceinline__ void solo_phase(const int lane, const int i0, const int i1,
                                           float4* pp, float* deaths,
                                           float& pjx, float& pjy, float& pjz) {
    v2f px2[K / 2], py2[K / 2], pz2[K / 2];
    unsigned m[K], idxs[K];
    unsigned vis = 0u;
#pragma unroll
    for (int r = 0; r < K; ++r) {
        const int slot = r * 64 + lane;
        idxs[r] = (unsigned)slot;
        float4 p = pp[slot];
        if (r & 1) { px2[r >> 1].y = p.x; py2[r >> 1].y = p.y; pz2[r >> 1].y = p.z; }
        else       { px2[r >> 1].x = p.x; py2[r >> 1].x = p.y; pz2[r >> 1].x = p.z; }
        if (FIRST) m[r] = 0x7F800000u | (unsigned)slot;   // +inf packed | slot
        else       m[r] = __float_as_uint(p.w);            // carried key
    }
    if (FIRST) {
        if (lane == 0) vis |= 1u;                          // start vertex (slot 0)
#pragma unroll
        for (int r = 0; r < K; ++r)
            if (r * 64 + lane >= N_PTS) vis |= 1u << r;    // pad slots 2046,2047
    }

#pragma unroll 1
    for (int i = i0; i < i1; ++i) {
        v2f jx = {pjx, pjx}, jy = {pjy, pjy}, jz = {pjz, pjz};
        unsigned lv0 = 0xFFFFFFFFu, lv1 = 0xFFFFFFFFu;
        unsigned lv2 = 0xFFFFFFFFu, lv3 = 0xFFFFFFFFu;
#pragma unroll
        for (int k2 = 0; k2 < K / 2; ++k2) {
            v2f dx = px2[k2] - jx, dy = py2[k2] - jy, dz = pz2[k2] - jz;
            v2f d2 = dx * dx + dy * dy + dz * dz;
            unsigned pk0 = (__float_as_uint(d2.x) & 0xFFFFF000u) | idxs[2 * k2];
            unsigned pk1 = (__float_as_uint(d2.y) & 0xFFFFF000u) | idxs[2 * k2 + 1];
            unsigned nm0 = m[2 * k2] < pk0 ? m[2 * k2] : pk0;
            unsigned nm1 = m[2 * k2 + 1] < pk1 ? m[2 * k2 + 1] : pk1;
            m[2 * k2] = nm0;
            m[2 * k2 + 1] = nm1;
            unsigned e0 = (unsigned)__builtin_amdgcn_sbfe((int)vis, 2 * k2, 1);
            unsigned e1 = (unsigned)__builtin_amdgcn_sbfe((int)vis, 2 * k2 + 1, 1);
            unsigned c0 = nm0 | e0, c1 = nm1 | e1;
            if ((k2 & 1) == 0) { lv0 = lv0 < c0 ? lv0 : c0; lv1 = lv1 < c1 ? lv1 : c1; }
            else               { lv2 = lv2 < c0 ? lv2 : c0; lv3 = lv3 < c1 ? lv3 : c1; }
        }
        unsigned lva = lv0 < lv1 ? lv0 : lv1;
        unsigned lvb = lv2 < lv3 ? lv2 : lv3;
        unsigned lv = lva < lvb ? lva : lvb;
        unsigned wmin = dpp_umin6(lv);                        // valid in lane 63
        unsigned w = (unsigned)__builtin_amdgcn_readlane((int)wmin, 63);  // SGPR bcast
        int j = (int)(w & 0x7FFu);
        if (lane == (j & 63)) vis |= 1u << (j >> 6);          // owner marks visited
        float4 pj = pp[j];                                    // broadcast ds_read_b128
        pjx = pj.x; pjy = pj.y; pjz = pj.z;
        if (lane == 0) deaths[i] = __uint_as_float(w & 0xFFFFF000u);  // raw trunc d2
    }

    if (COMPACT) {
        // survivors -> pp[0..rem): pos.xyz + repacked key (trunc d2 | new slot)
        unsigned ucnt = (unsigned)K - (unsigned)__popc(vis);
        unsigned inc = ucnt;
#pragma unroll
        for (int d = 1; d < 64; d <<= 1) {
            unsigned tt = (unsigned)__shfl_up((int)inc, d, 64);
            if (lane >= d) inc += tt;
        }
        unsigned base = inc - ucnt;                           // exclusive prefix
#pragma unroll
        for (int r = 0; r < K; ++r) {
            if (!((vis >> r) & 1u)) {
                float xx = (r & 1) ? px2[r >> 1].y : px2[r >> 1].x;
                float yy = (r & 1) ? py2[r >> 1].y : py2[r >> 1].x;
                float zz = (r & 1) ? pz2[r >> 1].y : pz2[r >> 1].x;
                pp[base] = make_float4(xx, yy, zz,
                                       __uint_as_float((m[r] & 0xFFFFF000u) | base));
                ++base;
            }
        }
    }
}

__global__ __launch_bounds__(TPB)
void topo_kernel(const float* __restrict__ pred,
                 const float* __restrict__ tgt,
                 float* __restrict__ topo /* [64][N_DEATH] */,
                 unsigned* __restrict__ ctr,
                 int fuse,
                 float* __restrict__ out) {
    __shared__ float4 pp[SORT_N];        // pos.xyz + (compacted phases) key in .w
    __shared__ float deaths[SORT_N];     // raw trunc d2 during Prim
    __shared__ unsigned lastflag;

    const int b = blockIdx.x;
    const float* x = (b < BATCH) ? (pred + b * LLEN) : (tgt + (b - BATCH) * LLEN);
    const int t = threadIdx.x;
    const int lane = t & 63;
    const int wid = t >> 6;

    // all 256 threads fill pp (coalesced); pads zeroed
#pragma unroll
    for (int s = 0; s < 8; ++s) {
        int idx = t * 8 + s;
        bool valid = idx < N_PTS;
        float vx = valid ? x[idx]     : 0.f;
        float vy = valid ? x[idx + 1] : 0.f;
        float vz = valid ? x[idx + 2] : 0.f;
        pp[idx] = make_float4(vx, vy, vz, 0.f);
    }
    __syncthreads();   // pp[] visible (barrier #1, all waves)

    if (wid == 0) {
        // --- solo Prim: NO barriers anywhere in here ---
        float4 p0 = pp[0];
        float pjx = p0.x, pjy = p0.y, pjz = p0.z;
        // phase schedule: compact when remaining == 64*Knext
        solo_phase<32, true,  true >(lane, 0,    509,  pp, deaths, pjx, pjy, pjz);
        solo_phase<24, false, true >(lane, 509,  1021, pp, deaths, pjx, pjy, pjz);
        solo_phase<16, false, true >(lane, 1021, 1277, pp, deaths, pjx, pjy, pjz);
        solo_phase<12, false, true >(lane, 1277, 1533, pp, deaths, pjx, pjy, pjz);
        solo_phase<8,  false, true >(lane, 1533, 1661, pp, deaths, pjx, pjy, pjz);
        solo_phase<6,  false, true >(lane, 1661, 1789, pp, deaths, pjx, pjy, pjz);
        solo_phase<4,  false, true >(lane, 1789, 1917, pp, deaths, pjx, pjy, pjz);
        solo_phase<2,  false, false>(lane, 1917, 2045, pp, deaths, pjx, pjy, pjz);
    }
    // waves 1-3 arrive here immediately and park at the barrier below;
    // wave 0 arrives after Prim -> release. Counts stay aligned because
    // the solo region contains zero barriers.
    if (t < SORT_N - N_DEATH) deaths[N_DEATH + t] = -BIG;   // t=0..2 (wave 0, post-Prim)
    __syncthreads();

    // bitonic sort DESCENDING on trunc d2 (sqrt is monotone -> same order)
    for (int k = 2; k <= SORT_N; k <<= 1) {
        for (int jj = k >> 1; jj > 0; jj >>= 1) {
#pragma unroll
            for (int s = 0; s < SORT_N / TPB; ++s) {
                int ii = t + s * TPB;
                int ixj = ii ^ jj;
                if (ixj > ii) {
                    float a = deaths[ii], c = deaths[ixj];
                    bool descBlock = ((ii & k) == 0);
                    bool doSwap = descBlock ? (a < c) : (a > c);
                    if (doSwap) { deaths[ii] = c; deaths[ixj] = a; }
                }
            }
            __syncthreads();
        }
    }

    for (int e = t; e < N_DEATH; e += TPB)
        topo[b * N_DEATH + e] = sqrtf(deaths[e]);   // sqrt deferred to here

    if (!fuse) return;

    // ---- fused loss: last-finishing block computes the full reduction ----
    __syncthreads();
    if (t == 0) {
        __threadfence();   // release: make topo visible across XCDs
        unsigned prev = __hip_atomic_fetch_add(ctr, 1u, __ATOMIC_ACQ_REL,
                                               __HIP_MEMORY_SCOPE_AGENT);
        lastflag = (prev == 63u) ? 1u : 0u;
        __threadfence();   // acquire before cross-XCD reads
    }
    __syncthreads();
    if (lastflag == 0u) return;

    float msum = 0.f;
    const float4* p4 = (const float4*)pred;
    const float4* t4 = (const float4*)tgt;
    for (int e = t; e < (BATCH * LLEN) / 4; e += TPB) {   // 16384 float4 pairs
        float4 a = p4[e], c = t4[e];
        float dx = a.x - c.x, dy = a.y - c.y, dz = a.z - c.z, dw = a.w - c.w;
        msum += dx * dx + dy * dy + dz * dz + dw * dw;
    }
    float tsum = 0.f;
    const float4* q4 = (const float4*)topo;
    const int nt4 = (BATCH * N_DEATH) / 4;   // 16360
    for (int e = t; e < nt4; e += TPB) {
        float4 a = q4[e], c = q4[e + nt4];
        float dx = a.x - c.x, dy = a.y - c.y, dz = a.z - c.z, dw = a.w - c.w;
        tsum += dx * dx + dy * dy + dz * dz + dw * dw;
    }
    __shared__ float sm[2][NW];
#pragma unroll
    for (int off = 32; off >= 1; off >>= 1) {
        msum += __shfl_xor(msum, off);
        tsum += __shfl_xor(tsum, off);
    }
    if (lane == 0) { sm[0][wid] = msum; sm[1][wid] = tsum; }
    __syncthreads();
    if (t == 0) {
        float M = 0.f, T = 0.f;
#pragma unroll
        for (int w = 0; w < NW; ++w) { M += sm[0][w]; T += sm[1][w]; }
        out[0] = M / (float)(BATCH * LLEN) + 0.1f * (T / (float)(BATCH * N_DEATH));
    }
}

// Fallback: single-block deterministic reduction (if ws can't hold the counter)
#define RTPB 1024
__global__ __launch_bounds__(RTPB)
void loss_kernel(const float* __restrict__ pred,
                 const float* __restrict__ tgt,
                 const float* __restrict__ topo,
                 float* __restrict__ out) {
    const int t = threadIdx.x;
    float msum = 0.f;
    const float4* p4 = (const float4*)pred;
    const float4* t4 = (const float4*)tgt;
    const int n4 = (BATCH * LLEN) / 4;   // 16384
    for (int e = t; e < n4; e += RTPB) {
        float4 a = p4[e], c = t4[e];
        float dx = a.x - c.x, dy = a.y - c.y, dz = a.z - c.z, dw = a.w - c.w;
        msum += dx * dx + dy * dy + dz * dz + dw * dw;
    }
    float tsum = 0.f;
    const int nt = BATCH * N_DEATH;      // 65440
    for (int e = t; e < nt; e += RTPB) {
        float d = topo[e] - topo[e + nt];
        tsum += d * d;
    }
    __shared__ float sm[2][RTPB / 64];
#pragma unroll
    for (int off = 32; off >= 1; off >>= 1) {
        msum += __shfl_xor(msum, off);
        tsum += __shfl_xor(tsum, off);
    }
    int lane = t & 63, wid = t >> 6;
    if (lane == 0) { sm[0][wid] = msum; sm[1][wid] = tsum; }
    __syncthreads();
    if (t == 0) {
        float M = 0.f, T = 0.f;
#pragma unroll
        for (int w = 0; w < RTPB / 64; ++w) { M += sm[0][w]; T += sm[1][w]; }
        out[0] = M / (float)(BATCH * LLEN) + 0.1f * (T / (float)nt);
    }
}

extern "C" void kernel_launch(void* const* d_in, const int* in_sizes, int n_in,
                              void* d_out, int out_size, void* d_ws, size_t ws_size,
                              hipStream_t stream) {
    const float* pred = (const float*)d_in[0];
    const float* tgt  = (const float*)d_in[1];
    float* topo = (float*)d_ws;
    unsigned* ctr = (unsigned*)((char*)d_ws + TOPO_BYTES);
    const int fuse = (ws_size >= TOPO_BYTES + sizeof(unsigned)) ? 1 : 0;

    if (fuse) hipMemsetAsync(ctr, 0, sizeof(unsigned), stream);  // re-arm per replay

    topo_kernel<<<2 * BATCH, TPB, 0, stream>>>(pred, tgt, topo,
                                               fuse ? ctr : nullptr, fuse,
                                               (float*)d_out);
    if (!fuse)
        loss_kernel<<<1, RTPB, 0, stream>>>(pred, tgt, topo, (float*)d_out);
}

// Round 4
// 630.747 us; speedup vs baseline: 1.4325x; 1.4325x over previous
//
#include <hip/hip_runtime.h>
#include <math.h>

// Problem constants (reference: B=32, L=2048)
#define LLEN 2048
#define BATCH 32
#define N_PTS (LLEN - 2)     // 2046 embedded points
#define N_DEATH (LLEN - 3)   // 2045 MST edges / deaths
#define SORT_N 2048
#define TPB 256              // 4 waves, one per SIMD
#define NW 4
#define BIG 1e30f
#define TOPO_BYTES ((size_t)64 * N_DEATH * 4)   // 523,520 B

typedef float v2f __attribute__((ext_vector_type(2)));

// Wave64 unsigned-min via DPP (VALU pipe). Result valid in lane 63.
__device__ __forceinline__ unsigned dpp_umin6(unsigned v) {
    unsigned t;
    t = (unsigned)__builtin_amdgcn_update_dpp(-1, (int)v, 0x111, 0xF, 0xF, false); // row_shr:1
    v = t < v ? t : v;
    t = (unsigned)__builtin_amdgcn_update_dpp(-1, (int)v, 0x112, 0xF, 0xF, false); // row_shr:2
    v = t < v ? t : v;
    t = (unsigned)__builtin_amdgcn_update_dpp(-1, (int)v, 0x114, 0xF, 0xF, false); // row_shr:4
    v = t < v ? t : v;
    t = (unsigned)__builtin_amdgcn_update_dpp(-1, (int)v, 0x118, 0xF, 0xF, false); // row_shr:8
    v = t < v ? t : v;
    t = (unsigned)__builtin_amdgcn_update_dpp(-1, (int)v, 0x142, 0xF, 0xF, false); // row_bcast:15
    v = t < v ? t : v;
    t = (unsigned)__builtin_amdgcn_update_dpp(-1, (int)v, 0x143, 0xF, 0xF, false); // row_bcast:31
    v = t < v ? t : v;
    return v;
}

// ROUND-9: r2's proven 4-wave barrier-exchange Prim (661 us) + BLOCK-WIDE
// progressive compaction. Post-mortem r3: solo wave = latency-starved
// (active-CU VALUBusy 17%); scan is the biggest chain segment (~256 of
// 776 cyc/iter, scalar — v2f does not emit v_pk). Keep 4-wave split,
// shrink scan: when unvisited <= 256*PTnext, all threads write survivors
// (pos + carried key in .w) to pp[0..rem) via block prefix-sum, reload
// with smaller PT. Phases PT 8/6/4/2 at i=509/1021/1533. Strided
// ownership idx = s*256+t (owner = j&255, bit = j>>8) avoids division.
// Tie-break insensitivity of the sorted death multiset: HW-proven in r3
// (absmax=0 with different tie-breaks). All barriers uniform across the
// block -> raw s_barrier counts stay aligned.
template<int PT, bool FIRST, bool COMPACT>
__device__ __forceinline__ void prim_phase(
    const int t, const int lane, const int wid,
    const int i0, const int i1, const unsigned rem_in,
    float4* __restrict__ pp, float* __restrict__ deaths,
    unsigned* __restrict__ xslot, unsigned* __restrict__ wtot,
    float& pjx, float& pjy, float& pjz)
{
    v2f px2[PT / 2], py2[PT / 2], pz2[PT / 2];
    unsigned m[PT];
    unsigned vis = 0u;
#pragma unroll
    for (int s = 0; s < PT; ++s) {
        const int idx = s * 256 + t;
        float4 p = pp[idx];
        if (s & 1) { px2[s >> 1].y = p.x; py2[s >> 1].y = p.y; pz2[s >> 1].y = p.z; }
        else       { px2[s >> 1].x = p.x; py2[s >> 1].x = p.y; pz2[s >> 1].x = p.z; }
        if (FIRST) {
            m[s] = 0x7F800000u | (unsigned)idx;           // +inf packed | idx
            if (idx >= (int)rem_in || idx == 0) vis |= 1u << s;  // pads + start
        } else {
            m[s] = __float_as_uint(p.w);                  // carried key
            if (idx >= (int)rem_in) vis |= 1u << s;       // empty slots
        }
    }

#pragma unroll 1
    for (int i = i0; i < i1; ++i) {
        v2f jx = {pjx, pjx}, jy = {pjy, pjy}, jz = {pjz, pjz};
        unsigned lv0 = 0xFFFFFFFFu, lv1 = 0xFFFFFFFFu;
#pragma unroll
        for (int k = 0; k < PT / 2; ++k) {
            v2f dx = px2[k] - jx, dy = py2[k] - jy, dz = pz2[k] - jz;
            v2f d2 = dx * dx + dy * dy + dz * dz;
            unsigned pk0 = (__float_as_uint(d2.x) & 0xFFFFF000u) | (unsigned)((2 * k) * 256 + t);
            unsigned pk1 = (__float_as_uint(d2.y) & 0xFFFFF000u) | (unsigned)((2 * k + 1) * 256 + t);
            unsigned nm0 = m[2 * k] < pk0 ? m[2 * k] : pk0;
            unsigned nm1 = m[2 * k + 1] < pk1 ? m[2 * k + 1] : pk1;
            m[2 * k] = nm0;
            m[2 * k + 1] = nm1;
            unsigned e0 = (unsigned)__builtin_amdgcn_sbfe((int)vis, 2 * k, 1);
            unsigned e1 = (unsigned)__builtin_amdgcn_sbfe((int)vis, 2 * k + 1, 1);
            unsigned c0 = nm0 | e0, c1 = nm1 | e1;
            lv0 = lv0 < c0 ? lv0 : c0;
            lv1 = lv1 < c1 ? lv1 : c1;
        }
        unsigned lv = lv0 < lv1 ? lv0 : lv1;
        unsigned wmin = dpp_umin6(lv);           // valid in lane 63
        const int base = (i & 1) * NW;
        if (lane == 63) xslot[base + wid] = wmin;
        // raw barrier: publish write lands before post-release reads (DS
        // FIFO within CU) — pattern HW-proven in r2 (absmax=0).
        asm volatile("s_barrier" ::: "memory");
        const uint4 q = *(const uint4*)&xslot[base];  // one b128 broadcast read
        unsigned w01 = q.x < q.y ? q.x : q.y;
        unsigned w23 = q.z < q.w ? q.z : q.w;
        unsigned win = w01 < w23 ? w01 : w23;
        int j = (int)(win & 0x7FFu);
        vis |= (t == (j & 255)) ? (1u << (j >> 8)) : 0u;   // owner marks visited
        float4 pj = pp[j];                       // broadcast read, conflict-free
        pjx = pj.x; pjy = pj.y; pjz = pj.z;
        if (t == 0) deaths[i] = __uint_as_float(win & 0xFFFFF000u); // raw d2
    }

    if (COMPACT) {
        // block-wide compaction: survivors -> pp[0..rem_out) with keys in .w
        const unsigned livemask = ~vis & ((1u << PT) - 1u);
        const unsigned cnt = (unsigned)__popc(livemask);
        unsigned inc = cnt;
#pragma unroll
        for (int d = 1; d < 64; d <<= 1) {
            unsigned tt = (unsigned)__shfl_up((int)inc, d, 64);
            if (lane >= d) inc += tt;
        }
        if (lane == 63) wtot[wid] = inc;         // wave totals
        // barrier: wtot visible; also guarantees every wave's last pp[j]
        // read retired (pj was consumed before arrival) -> writes are safe.
        asm volatile("s_barrier" ::: "memory");
        unsigned wbase = 0;
#pragma unroll
        for (int w = 0; w < NW; ++w) wbase += (w < wid) ? wtot[w] : 0u;
        unsigned dst = wbase + inc - cnt;        // exclusive prefix, block-wide
#pragma unroll
        for (int s = 0; s < PT; ++s) {
            if ((livemask >> s) & 1u) {
                float xx = (s & 1) ? px2[s >> 1].y : px2[s >> 1].x;
                float yy = (s & 1) ? py2[s >> 1].y : py2[s >> 1].x;
                float zz = (s & 1) ? pz2[s >> 1].y : pz2[s >> 1].x;
                pp[dst] = make_float4(xx, yy, zz,
                                      __uint_as_float((m[s] & 0xFFFFF000u) | dst));
                ++dst;
            }
        }
        asm volatile("s_barrier" ::: "memory");  // compacted pp visible to reload
    }
}

__global__ __launch_bounds__(TPB)
void topo_kernel(const float* __restrict__ pred,
                 const float* __restrict__ tgt,
                 float* __restrict__ topo /* [64][N_DEATH] */,
                 unsigned* __restrict__ ctr,
                 int fuse,
                 float* __restrict__ out) {
    __shared__ float4 pp[SORT_N];        // pos.xyz + (compacted) key in .w
    __shared__ float deaths[SORT_N];     // raw trunc d2 during Prim
    __shared__ __align__(16) unsigned xslot[2 * NW];  // [buf][wave]
    __shared__ unsigned wtot[NW];
    __shared__ unsigned lastflag;

    const int b = blockIdx.x;
    const float* x = (b < BATCH) ? (pred + b * LLEN) : (tgt + (b - BATCH) * LLEN);
    const int t = threadIdx.x;
    const int lane = t & 63;
    const int wid = t >> 6;

    // strided fill: idx = s*256+t, coalesced across t
#pragma unroll
    for (int s = 0; s < 8; ++s) {
        int idx = s * 256 + t;
        bool valid = idx < N_PTS;
        float vx = valid ? x[idx]     : 0.f;
        float vy = valid ? x[idx + 1] : 0.f;
        float vz = valid ? x[idx + 2] : 0.f;
        pp[idx] = make_float4(vx, vy, vz, 0.f);
    }
    __syncthreads();   // pp[] visible (real barrier)

    float pjx = x[0], pjy = x[1], pjz = x[2];

    // phase schedule: compact when unvisited-after == 256*PTnext
    prim_phase<8, true,  true >(t, lane, wid, 0,    509,  N_PTS, pp, deaths, xslot, wtot, pjx, pjy, pjz);
    prim_phase<6, false, true >(t, lane, wid, 509,  1021, 1536,  pp, deaths, xslot, wtot, pjx, pjy, pjz);
    prim_phase<4, false, true >(t, lane, wid, 1021, 1533, 1024,  pp, deaths, xslot, wtot, pjx, pjy, pjz);
    prim_phase<2, false, false>(t, lane, wid, 1533, 2045, 512,   pp, deaths, xslot, wtot, pjx, pjy, pjz);

    // pad then bitonic sort DESCENDING on trunc d2 (sqrt monotone)
    if (t < SORT_N - N_DEATH) deaths[N_DEATH + t] = -BIG;
    __syncthreads();

    for (int k = 2; k <= SORT_N; k <<= 1) {
        for (int jj = k >> 1; jj > 0; jj >>= 1) {
#pragma unroll
            for (int s = 0; s < SORT_N / TPB; ++s) {
                int ii = t + s * TPB;
                int ixj = ii ^ jj;
                if (ixj > ii) {
                    float a = deaths[ii], c = deaths[ixj];
                    bool descBlock = ((ii & k) == 0);
                    bool doSwap = descBlock ? (a < c) : (a > c);
                    if (doSwap) { deaths[ii] = c; deaths[ixj] = a; }
                }
            }
            __syncthreads();
        }
    }

    for (int e = t; e < N_DEATH; e += TPB)
        topo[b * N_DEATH + e] = sqrtf(deaths[e]);   // sqrt deferred to here

    if (!fuse) return;

    // ---- fused loss: last-finishing block computes the full reduction ----
    __syncthreads();
    if (t == 0) {
        __threadfence();   // release: make topo visible across XCDs
        unsigned prev = __hip_atomic_fetch_add(ctr, 1u, __ATOMIC_ACQ_REL,
                                               __HIP_MEMORY_SCOPE_AGENT);
        lastflag = (prev == 63u) ? 1u : 0u;
        __threadfence();   // acquire before cross-XCD reads
    }
    __syncthreads();
    if (lastflag == 0u) return;

    float msum = 0.f;
    const float4* p4 = (const float4*)pred;
    const float4* t4 = (const float4*)tgt;
    for (int e = t; e < (BATCH * LLEN) / 4; e += TPB) {   // 16384 float4 pairs
        float4 a = p4[e], c = t4[e];
        float dx = a.x - c.x, dy = a.y - c.y, dz = a.z - c.z, dw = a.w - c.w;
        msum += dx * dx + dy * dy + dz * dz + dw * dw;
    }
    float tsum = 0.f;
    const float4* q4 = (const float4*)topo;
    const int nt4 = (BATCH * N_DEATH) / 4;   // 16360
    for (int e = t; e < nt4; e += TPB) {
        float4 a = q4[e], c = q4[e + nt4];
        float dx = a.x - c.x, dy = a.y - c.y, dz = a.z - c.z, dw = a.w - c.w;
        tsum += dx * dx + dy * dy + dz * dz + dw * dw;
    }
    __shared__ float sm[2][NW];
#pragma unroll
    for (int off = 32; off >= 1; off >>= 1) {
        msum += __shfl_xor(msum, off);
        tsum += __shfl_xor(tsum, off);
    }
    if (lane == 0) { sm[0][wid] = msum; sm[1][wid] = tsum; }
    __syncthreads();
    if (t == 0) {
        float M = 0.f, T = 0.f;
#pragma unroll
        for (int w = 0; w < NW; ++w) { M += sm[0][w]; T += sm[1][w]; }
        out[0] = M / (float)(BATCH * LLEN) + 0.1f * (T / (float)(BATCH * N_DEATH));
    }
}

// Fallback: single-block deterministic reduction (if ws can't hold the counter)
#define RTPB 1024
__global__ __launch_bounds__(RTPB)
void loss_kernel(const float* __restrict__ pred,
                 const float* __restrict__ tgt,
                 const float* __restrict__ topo,
                 float* __restrict__ out) {
    const int t = threadIdx.x;
    float msum = 0.f;
    const float4* p4 = (const float4*)pred;
    const float4* t4 = (const float4*)tgt;
    const int n4 = (BATCH * LLEN) / 4;   // 16384
    for (int e = t; e < n4; e += RTPB) {
        float4 a = p4[e], c = t4[e];
        float dx = a.x - c.x, dy = a.y - c.y, dz = a.z - c.z, dw = a.w - c.w;
        msum += dx * dx + dy * dy + dz * dz + dw * dw;
    }
    float tsum = 0.f;
    const int nt = BATCH * N_DEATH;      // 65440
    for (int e = t; e < nt; e += RTPB) {
        float d = topo[e] - topo[e + nt];
        tsum += d * d;
    }
    __shared__ float sm[2][RTPB / 64];
#pragma unroll
    for (int off = 32; off >= 1; off >>= 1) {
        msum += __shfl_xor(msum, off);
        tsum += __shfl_xor(tsum, off);
    }
    int lane = t & 63, wid = t >> 6;
    if (lane == 0) { sm[0][wid] = msum; sm[1][wid] = tsum; }
    __syncthreads();
    if (t == 0) {
        float M = 0.f, T = 0.f;
#pragma unroll
        for (int w = 0; w < RTPB / 64; ++w) { M += sm[0][w]; T += sm[1][w]; }
        out[0] = M / (float)(BATCH * LLEN) + 0.1f * (T / (float)nt);
    }
}

extern "C" void kernel_launch(void* const* d_in, const int* in_sizes, int n_in,
                              void* d_out, int out_size, void* d_ws, size_t ws_size,
                              hipStream_t stream) {
    const float* pred = (const float*)d_in[0];
    const float* tgt  = (const float*)d_in[1];
    float* topo = (float*)d_ws;
    unsigned* ctr = (unsigned*)((char*)d_ws + TOPO_BYTES);
    const int fuse = (ws_size >= TOPO_BYTES + sizeof(unsigned)) ? 1 : 0;

    if (fuse) hipMemsetAsync(ctr, 0, sizeof(unsigned), stream);  // re-arm per replay

    topo_kernel<<<2 * BATCH, TPB, 0, stream>>>(pred, tgt, topo,
                                               fuse ? ctr : nullptr, fuse,
                                               (float*)d_out);
    if (!fuse)
        loss_kernel<<<1, RTPB, 0, stream>>>(pred, tgt, topo, (float*)d_out);
}